// Round 8
// baseline (180.966 us; speedup 1.0000x reference)
//
#include <hip/hip_runtime.h>

#define B_DIM 4096
#define I_DIM 1024
#define O_DIM 1024
#define ON_DIM 4096      // O * N fan-in columns
#define TILE_HALFS 4096  // one 128(m) x 32(k) fp16 tile image = 8 KB
                         // image order: [kb8(4)][m(128)][j(8)] halfs

typedef _Float16 half8  __attribute__((ext_vector_type(8)));
typedef _Float16 half4_t __attribute__((ext_vector_type(4)));
typedef float    floatx4 __attribute__((ext_vector_type(4)));

// ---------------------------------------------------------------------------
// Kernel P: fused prep (R7, kept) — softmax+tile in one pass, 2 launches.
// ---------------------------------------------------------------------------
__global__ __launch_bounds__(256)
void ltn_prep(const float* __restrict__ logits, const float* __restrict__ x,
              _Float16* __restrict__ wt, _Float16* __restrict__ xt) {
  const int t = threadIdx.x;
  if (blockIdx.x < 1024) {
    __shared__ _Float16 lbuf[4][1040];
    const int lane = t & 63, wv = t >> 6;
    const int row  = blockIdx.x * 4 + wv;          // ON row, 4-aligned base
    const int nb   = row >> 7;
    const int nnB  = (blockIdx.x * 4) & 127;       // base m within 128-tile
    const float4* s4 = (const float4*)(logits + (size_t)row * I_DIM);
    float4 v[4];
#pragma unroll
    for (int j = 0; j < 4; j++) v[j] = s4[lane * 4 + j];  // 64B/lane contig
    float m = -1e30f;
#pragma unroll
    for (int j = 0; j < 4; j++)
      m = fmaxf(m, fmaxf(fmaxf(v[j].x, v[j].y), fmaxf(v[j].z, v[j].w)));
#pragma unroll
    for (int off = 1; off < 64; off <<= 1) m = fmaxf(m, __shfl_xor(m, off));
    float s = 0.0f;
#pragma unroll
    for (int j = 0; j < 4; j++) {
      v[j].x = __expf(v[j].x - m); v[j].y = __expf(v[j].y - m);
      v[j].z = __expf(v[j].z - m); v[j].w = __expf(v[j].w - m);
      s += v[j].x + v[j].y + v[j].z + v[j].w;
    }
#pragma unroll
    for (int off = 1; off < 64; off <<= 1) s += __shfl_xor(s, off);
    const float inv = 1.0f / s;
#pragma unroll
    for (int j = 0; j < 4; j++) {
      half4_t h;
      h[0] = (_Float16)(v[j].x * inv); h[1] = (_Float16)(v[j].y * inv);
      h[2] = (_Float16)(v[j].z * inv); h[3] = (_Float16)(v[j].w * inv);
      *(half4_t*)&lbuf[wv][lane * 16 + j * 4] = h;   // k = lane*16+j*4..+3
    }
    __syncthreads();
#pragma unroll
    for (int p = 0; p < 2; p++) {
      const int u   = t + p * 256;
      const int nn4 = u & 3;
      const int kb8 = (u >> 2) & 3;
      const int kb  = u >> 4;
      const half8 h = *(const half8*)&lbuf[nn4][kb * 32 + kb8 * 8];
      _Float16* dst = wt + ((size_t)nb * 32 + kb) * TILE_HALFS
                    + kb8 * 1024 + (nnB + nn4) * 8;
      *(half8*)dst = h;
    }
  } else {
    const int bid = blockIdx.x - 1024;
    const int nn = t >> 1;        // row within 128-tile
    const int hf = t & 1;         // which 16-k half of the 32-k tile
    const int mb = bid >> 5, kt = bid & 31;
    const int row = mb * 128 + nn;
    const float4* src = (const float4*)(x + (size_t)row * I_DIM + kt * 32 + hf * 16);
    const float4 a = src[0], b = src[1], c = src[2], d = src[3];
    half8 h0, h1;
    h0[0] = (_Float16)a.x; h0[1] = (_Float16)a.y; h0[2] = (_Float16)a.z; h0[3] = (_Float16)a.w;
    h0[4] = (_Float16)b.x; h0[5] = (_Float16)b.y; h0[6] = (_Float16)b.z; h0[7] = (_Float16)b.w;
    h1[0] = (_Float16)c.x; h1[1] = (_Float16)c.y; h1[2] = (_Float16)c.z; h1[3] = (_Float16)c.w;
    h1[4] = (_Float16)d.x; h1[5] = (_Float16)d.y; h1[6] = (_Float16)d.z; h1[7] = (_Float16)d.w;
    _Float16* base = xt + ((size_t)mb * 32 + kt) * TILE_HALFS + (hf * 2) * 1024 + nn * 8;
    *(half8*)base = h0;
    *(half8*)(base + 1024) = h1;
  }
}

// ---------------------------------------------------------------------------
// GEMM + sigmoid + 16-corner LUT — EXACT R1 source (NO unroll-1 pragma: the
// compiler's x3 unroll makes the triple-buffer rotation offsets compile-time;
// R7's pragma collapsed prefetch distance -> profiled 120us, MfmaUtil 11%).
// R8 DIAGNOSTIC: this kernel is launched TWICE (idempotent, bit-identical
// out). The timed total now reads out the true warm GEMM time as
// (total - 132.8): ~132 => harness floor; ~187 => warm GEMM ~55us;
// ~250 => warm GEMM ~120us. Profile top-5 shows cold(1st) vs warm(2nd).
// ---------------------------------------------------------------------------
__global__ __launch_bounds__(512, 2)
void ltn_gemm_lut(const _Float16* __restrict__ xt,   // tiles [32*32][TILE_HALFS]
                  const _Float16* __restrict__ wt,
                  const float* __restrict__ lut,     // [O][16]
                  float* __restrict__ out) {         // [B][O]
  __shared__ _Float16 sm[3 * 16384];

  const int tid  = threadIdx.x;
  const int lane = tid & 63;
  const int wv   = tid >> 6;     // 0..7
  const int wr   = wv >> 1;      // row-wave 0..3  (64 rows each)
  const int wc   = wv & 1;       // col-wave 0..1  (128 cols each)

  const int id  = blockIdx.x;    // 0..255
  const int xcd = id & 7;
  const int li  = id >> 3;       // 0..31
  const int mb  = (xcd & 3) * 4 + (li & 3);
  const int nb  = (xcd >> 2) * 8 + (li >> 2);

  const int fm = lane & 15;
  const int kq = lane >> 4;

  const size_t baseA = (size_t)(mb * 2) * 32 * TILE_HALFS;
  const size_t baseB = (size_t)(nb * 2) * 32 * TILE_HALFS;

  floatx4 acc[4][8];
#pragma unroll
  for (int i = 0; i < 4; i++)
#pragma unroll
    for (int j = 0; j < 8; j++) acc[i][j] = (floatx4)0.0f;

  auto stage = [&](int bufOff /*halfs*/, int kt) {
#pragma unroll
    for (int s = 0; s < 4; s++) {
      const int c   = wv * 4 + s;        // 0..31, wave-uniform split
      const int cc  = c & 15;            // chunk within matrix
      const int tl  = cc >> 3;           // which 128-row tile (0/1)
      const int sub = cc & 7;            // 1KB sub-chunk
      const _Float16* g;
      int dst;
      if (c < 16) {
        g = xt + baseA + (size_t)(tl * 32 + kt) * TILE_HALFS + sub * 512 + lane * 8;
        dst = bufOff + cc * 512;
      } else {
        g = wt + baseB + (size_t)(tl * 32 + kt) * TILE_HALFS + sub * 512 + lane * 8;
        dst = bufOff + 8192 + cc * 512;
      }
      __builtin_amdgcn_global_load_lds(
          (const __attribute__((address_space(1))) void*)g,
          (__attribute__((address_space(3))) void*)(sm + dst), 16, 0, 0);
    }
  };

  auto compute = [&](int bufOff) {
    half8 af[4], bf[8];
#pragma unroll
    for (int f = 0; f < 4; f++)
      af[f] = *(const half8*)&sm[bufOff + ((wr >> 1) * 4 + kq) * 1024
                                 + ((wr & 1) * 64 + f * 16 + fm) * 8];
#pragma unroll
    for (int g = 0; g < 8; g++)
      bf[g] = *(const half8*)&sm[bufOff + 8192 + (wc * 4 + kq) * 1024
                                 + (g * 16 + fm) * 8];
    __builtin_amdgcn_s_setprio(1);
#pragma unroll
    for (int mt = 0; mt < 4; mt++)
#pragma unroll
      for (int nt = 0; nt < 8; nt++)
        acc[mt][nt] = __builtin_amdgcn_mfma_f32_16x16x32_f16(
            af[mt], bf[nt], acc[mt][nt], 0, 0, 0);
    __builtin_amdgcn_s_setprio(0);
  };

  stage(0, 0);
  stage(16384, 1);
  int o0 = 0, o1 = 16384, o2 = 32768;   // read buf, in-flight buf, free buf

  for (int kt = 0; kt < 32; kt++) {
    if (kt < 31) asm volatile("s_waitcnt vmcnt(4)" ::: "memory");
    else         asm volatile("s_waitcnt vmcnt(0)" ::: "memory");
    __builtin_amdgcn_s_barrier();
    __builtin_amdgcn_sched_barrier(0);
    if (kt + 2 < 32) stage(o2, kt + 2);  // o2 held kt-1: reads done pre-barrier
    compute(o0);
    const int t0 = o0; o0 = o1; o1 = o2; o2 = t0;
  }

  // ---- fused epilogue: sigmoid -> gather 4 fan-in values -> LUT contraction
#pragma unroll
  for (int nt = 0; nt < 8; nt++) {
    const int o = (nb * 256 + wc * 128 + nt * 16 + fm) >> 2;
    const float4* lt4 = (const float4*)(lut + (size_t)o * 16);
    const float4 L0 = lt4[0], L1 = lt4[1], L2 = lt4[2], L3 = lt4[3];
#pragma unroll
    for (int mt = 0; mt < 4; mt++) {
#pragma unroll
      for (int r = 0; r < 4; r++) {
        const float v  = acc[mt][nt][r];
        const float sv = 1.0f / (1.0f + __expf(-v));
        const float s1 = __shfl_down(sv, 1);
        const float s2 = __shfl_down(sv, 2);
        const float s3 = __shfl_down(sv, 3);
        if ((lane & 3) == 0) {
          const float s0 = sv;
          const float a0 = L0.x + (L2.x - L0.x) * s3;
          const float a1 = L0.y + (L2.y - L0.y) * s3;
          const float a2 = L0.z + (L2.z - L0.z) * s3;
          const float a3 = L0.w + (L2.w - L0.w) * s3;
          const float a4 = L1.x + (L3.x - L1.x) * s3;
          const float a5 = L1.y + (L3.y - L1.y) * s3;
          const float a6 = L1.z + (L3.z - L1.z) * s3;
          const float a7 = L1.w + (L3.w - L1.w) * s3;
          const float b0 = a0 + (a4 - a0) * s2;
          const float b1 = a1 + (a5 - a1) * s2;
          const float b2 = a2 + (a6 - a2) * s2;
          const float b3 = a3 + (a7 - a3) * s2;
          const float c0 = b0 + (b2 - b0) * s1;
          const float c1 = b1 + (b3 - b1) * s1;
          const float res = c0 + (c1 - c0) * s0;
          const int row = mb * 256 + wr * 64 + mt * 16 + (lane >> 4) * 4 + r;
          out[(size_t)row * O_DIM + o] = res;
        }
      }
    }
  }
}

// ---------------------------------------------------------------------------
extern "C" void kernel_launch(void* const* d_in, const int* in_sizes, int n_in,
                              void* d_out, int out_size, void* d_ws, size_t ws_size,
                              hipStream_t stream) {
  const float* x      = (const float*)d_in[0];  // (B, I)
  const float* logits = (const float*)d_in[1];  // (O, N, I)
  const float* lut    = (const float*)d_in[2];  // (O, 16)
  float* out          = (float*)d_out;          // (B, O)

  _Float16* wt = (_Float16*)d_ws;                                  // 8 MB tiled
  _Float16* xt = (_Float16*)d_ws + (size_t)ON_DIM * I_DIM;         // 8 MB tiled

  ltn_prep<<<2048, 256, 0, stream>>>(logits, x, wt, xt);
  // R8 diagnostic: GEMM twice (idempotent). total - 132.8 = true warm GEMM.
  ltn_gemm_lut<<<256, 512, 0, stream>>>(xt, wt, lut, out);
  ltn_gemm_lut<<<256, 512, 0, stream>>>(xt, wt, lut, out);
}

// Round 9
// 134.995 us; speedup vs baseline: 1.3405x; 1.3405x over previous
//
#include <hip/hip_runtime.h>

#define B_DIM 4096
#define I_DIM 1024
#define O_DIM 1024
#define ON_DIM 4096      // O * N fan-in columns
#define TILE_HALFS 4096  // one 128(m) x 32(k) fp16 tile image = 8 KB
                         // image order: [kb8(4)][m(128)][j(8)] halfs

typedef _Float16 half8  __attribute__((ext_vector_type(8)));
typedef _Float16 half4_t __attribute__((ext_vector_type(4)));
typedef float    floatx4 __attribute__((ext_vector_type(4)));

// ---------------------------------------------------------------------------
// Kernel P: fused prep (R7, kept) — softmax+tile in one pass, 2 launches.
// ---------------------------------------------------------------------------
__global__ __launch_bounds__(256)
void ltn_prep(const float* __restrict__ logits, const float* __restrict__ x,
              _Float16* __restrict__ wt, _Float16* __restrict__ xt) {
  const int t = threadIdx.x;
  if (blockIdx.x < 1024) {
    __shared__ _Float16 lbuf[4][1040];
    const int lane = t & 63, wv = t >> 6;
    const int row  = blockIdx.x * 4 + wv;          // ON row, 4-aligned base
    const int nb   = row >> 7;
    const int nnB  = (blockIdx.x * 4) & 127;       // base m within 128-tile
    const float4* s4 = (const float4*)(logits + (size_t)row * I_DIM);
    float4 v[4];
#pragma unroll
    for (int j = 0; j < 4; j++) v[j] = s4[lane * 4 + j];  // 64B/lane contig
    float m = -1e30f;
#pragma unroll
    for (int j = 0; j < 4; j++)
      m = fmaxf(m, fmaxf(fmaxf(v[j].x, v[j].y), fmaxf(v[j].z, v[j].w)));
#pragma unroll
    for (int off = 1; off < 64; off <<= 1) m = fmaxf(m, __shfl_xor(m, off));
    float s = 0.0f;
#pragma unroll
    for (int j = 0; j < 4; j++) {
      v[j].x = __expf(v[j].x - m); v[j].y = __expf(v[j].y - m);
      v[j].z = __expf(v[j].z - m); v[j].w = __expf(v[j].w - m);
      s += v[j].x + v[j].y + v[j].z + v[j].w;
    }
#pragma unroll
    for (int off = 1; off < 64; off <<= 1) s += __shfl_xor(s, off);
    const float inv = 1.0f / s;
#pragma unroll
    for (int j = 0; j < 4; j++) {
      half4_t h;
      h[0] = (_Float16)(v[j].x * inv); h[1] = (_Float16)(v[j].y * inv);
      h[2] = (_Float16)(v[j].z * inv); h[3] = (_Float16)(v[j].w * inv);
      *(half4_t*)&lbuf[wv][lane * 16 + j * 4] = h;   // k = lane*16+j*4..+3
    }
    __syncthreads();
#pragma unroll
    for (int p = 0; p < 2; p++) {
      const int u   = t + p * 256;
      const int nn4 = u & 3;
      const int kb8 = (u >> 2) & 3;
      const int kb  = u >> 4;
      const half8 h = *(const half8*)&lbuf[nn4][kb * 32 + kb8 * 8];
      _Float16* dst = wt + ((size_t)nb * 32 + kb) * TILE_HALFS
                    + kb8 * 1024 + (nnB + nn4) * 8;
      *(half8*)dst = h;
    }
  } else {
    const int bid = blockIdx.x - 1024;
    const int nn = t >> 1;        // row within 128-tile
    const int hf = t & 1;         // which 16-k half of the 32-k tile
    const int mb = bid >> 5, kt = bid & 31;
    const int row = mb * 128 + nn;
    const float4* src = (const float4*)(x + (size_t)row * I_DIM + kt * 32 + hf * 16);
    const float4 a = src[0], b = src[1], c = src[2], d = src[3];
    half8 h0, h1;
    h0[0] = (_Float16)a.x; h0[1] = (_Float16)a.y; h0[2] = (_Float16)a.z; h0[3] = (_Float16)a.w;
    h0[4] = (_Float16)b.x; h0[5] = (_Float16)b.y; h0[6] = (_Float16)b.z; h0[7] = (_Float16)b.w;
    h1[0] = (_Float16)c.x; h1[1] = (_Float16)c.y; h1[2] = (_Float16)c.z; h1[3] = (_Float16)c.w;
    h1[4] = (_Float16)d.x; h1[5] = (_Float16)d.y; h1[6] = (_Float16)d.z; h1[7] = (_Float16)d.w;
    _Float16* base = xt + ((size_t)mb * 32 + kt) * TILE_HALFS + (hf * 2) * 1024 + nn * 8;
    *(half8*)base = h0;
    *(half8*)(base + 1024) = h1;
  }
}

// ---------------------------------------------------------------------------
// GEMM + sigmoid + 16-corner LUT.  R9: BARRIER-FREE free-running wave
// pipelines. R8 decoded the measurements: profiled times are COLD replays
// (rocprof flushes caches; GEMM#2 re-fetched 25MB); the WARM GEMM is 48us
// for ALL five prior schedules including the prefetch-crippled one ->
// warm floor = serialization of LDS-drain + MFMA + VALU under per-step
// barriers that phase-lock all waves (serial sum ~3600cy/step = measured).
// Fix: NO cross-wave sharing, NO s_barrier in the K-loop.
//   - 8 waves, each owns a 64x128 C-tile (wr=wv>>1 row-quad, wc=wv&1).
//   - B-panel slice staged PRIVATELY: 2x8KB ring per wave (128KB LDS),
//     global_load_lds, per-wave counted vmcnt(12) ledger.
//     (>=12 newest outstanding are iter kt-1's; everything older --
//     i.e. this iter's B and A -- is guaranteed retired. Safe even if
//     the compiler splits A-loads: count can only grow.)
//   - A-fragments stream L2->REGISTERS (no LDS), ping-pong 2-deep with
//     STATIC indexing (afA/afB named arrays, manual unroll-2).
//   - GLL into the just-read buffer only after lgkmcnt(0) (reads retired).
// Waves de-phase -> ds_read/GLL/VALU overlap MFMA across the 2 waves/SIMD.
// ---------------------------------------------------------------------------
__global__ __launch_bounds__(512, 2)
void ltn_gemm_lut(const _Float16* __restrict__ xt,   // tiles [32*32][TILE_HALFS]
                  const _Float16* __restrict__ wt,
                  const float* __restrict__ lut,     // [O][16]
                  float* __restrict__ out) {         // [B][O]
  __shared__ _Float16 sm[8 * 8192];    // per wave: 2 x 4096-half B buffers

  const int tid  = threadIdx.x;
  const int lane = tid & 63;
  const int wv   = tid >> 6;     // 0..7
  const int wr   = wv >> 1;      // row-wave 0..3  (64 rows each)
  const int wc   = wv & 1;       // col-wave 0..1  (128 cols each)

  // XCD-chunked swizzle (kept: dedup of A/B panels happens in per-XCD L2).
  const int id  = blockIdx.x;    // 0..255
  const int xcd = id & 7;
  const int li  = id >> 3;       // 0..31
  const int mb  = (xcd & 3) * 4 + (li & 3);
  const int nb  = (xcd >> 2) * 8 + (li >> 2);

  const int fm = lane & 15;
  const int kq = lane >> 4;

  // A image for this wave: 128-row tile (mb*2 + (wr>>1)), row window (wr&1)*64.
  const _Float16* xA = xt + (size_t)(mb * 2 + (wr >> 1)) * 32 * TILE_HALFS;
  const int ro = (wr & 1) * 64;
  const int laneA = kq * 1024 + (ro + fm) * 8;       // + f*128 per m-tile
  // B image for this wave: 128-col tile (nb*2 + wc), full 128 rows.
  const _Float16* wB = wt + (size_t)(nb * 2 + wc) * 32 * TILE_HALFS;
  const int laneB = kq * 1024 + fm * 8;              // + g*128 per n-tile
  _Float16* myB = sm + wv * 8192;                    // + buf*4096 + c*512

  floatx4 acc[4][8];
#pragma unroll
  for (int i = 0; i < 4; i++)
#pragma unroll
    for (int j = 0; j < 8; j++) acc[i][j] = (floatx4)0.0f;

  auto stageB = [&](int buf, int kt) {
    const _Float16* img = wB + (size_t)kt * TILE_HALFS;
#pragma unroll
    for (int c = 0; c < 8; c++) {
      __builtin_amdgcn_global_load_lds(
          (const __attribute__((address_space(1))) void*)(img + c * 512 + lane * 8),
          (__attribute__((address_space(3))) void*)(myB + buf * 4096 + c * 512),
          16, 0, 0);
    }
  };

  half8 afA[4], afB[4];
  auto loadA = [&](half8 (&af)[4], int kt) {
    const _Float16* img = xA + (size_t)kt * TILE_HALFS;
#pragma unroll
    for (int f = 0; f < 4; f++)
      af[f] = *(const half8*)(img + laneA + f * 128);
  };

  // Prologue: B(0),B(1) staged; A(0)->afA, A(1)->afB. 24+ VMEM outstanding.
  stageB(0, 0);
  stageB(1, 1);
  loadA(afA, 0);
  loadA(afB, 1);

  auto body = [&](int kt, half8 (&af)[4], int buf) {
    // All-but-12-newest retired => B(kt) in LDS, A(kt) regs vmcnt'd by compiler.
    if (kt < 30) asm volatile("s_waitcnt vmcnt(12)" ::: "memory");
    else         asm volatile("s_waitcnt vmcnt(0)"  ::: "memory");
    __builtin_amdgcn_sched_barrier(0);
    half8 bf[8];
#pragma unroll
    for (int g = 0; g < 8; g++)
      bf[g] = *(const half8*)(myB + buf * 4096 + laneB + g * 128);
    asm volatile("s_waitcnt lgkmcnt(0)" ::: "memory");   // bf retired to regs
    __builtin_amdgcn_sched_barrier(0);
    if (kt + 2 < 32) stageB(buf, kt + 2);   // safe: reads of buf retired
    __builtin_amdgcn_sched_barrier(0);
    __builtin_amdgcn_s_setprio(1);
#pragma unroll
    for (int mt = 0; mt < 4; mt++)
#pragma unroll
      for (int nt = 0; nt < 8; nt++)
        acc[mt][nt] = __builtin_amdgcn_mfma_f32_16x16x32_f16(
            af[mt], bf[nt], acc[mt][nt], 0, 0, 0);
    __builtin_amdgcn_s_setprio(0);
    if (kt + 2 < 32) loadA(af, kt + 2);     // af regs free after MFMA cluster
    __builtin_amdgcn_sched_barrier(0);
  };

#pragma unroll 1
  for (int k2 = 0; k2 < 16; k2++) {
    body(2 * k2,     afA, 0);
    body(2 * k2 + 1, afB, 1);
  }

  // ---- fused epilogue: sigmoid -> gather 4 fan-in values -> LUT contraction
  // (identical to R1; per-wave private, no sync needed)
#pragma unroll
  for (int nt = 0; nt < 8; nt++) {
    const int o = (nb * 256 + wc * 128 + nt * 16 + fm) >> 2;
    const float4* lt4 = (const float4*)(lut + (size_t)o * 16);
    const float4 L0 = lt4[0], L1 = lt4[1], L2 = lt4[2], L3 = lt4[3];
#pragma unroll
    for (int mt = 0; mt < 4; mt++) {
#pragma unroll
      for (int r = 0; r < 4; r++) {
        const float v  = acc[mt][nt][r];
        const float sv = 1.0f / (1.0f + __expf(-v));
        const float s1 = __shfl_down(sv, 1);
        const float s2 = __shfl_down(sv, 2);
        const float s3 = __shfl_down(sv, 3);
        if ((lane & 3) == 0) {
          const float s0 = sv;
          const float a0 = L0.x + (L2.x - L0.x) * s3;
          const float a1 = L0.y + (L2.y - L0.y) * s3;
          const float a2 = L0.z + (L2.z - L0.z) * s3;
          const float a3 = L0.w + (L2.w - L0.w) * s3;
          const float a4 = L1.x + (L3.x - L1.x) * s3;
          const float a5 = L1.y + (L3.y - L1.y) * s3;
          const float a6 = L1.z + (L3.z - L1.z) * s3;
          const float a7 = L1.w + (L3.w - L1.w) * s3;
          const float b0 = a0 + (a4 - a0) * s2;
          const float b1 = a1 + (a5 - a1) * s2;
          const float b2 = a2 + (a6 - a2) * s2;
          const float b3 = a3 + (a7 - a3) * s2;
          const float c0 = b0 + (b2 - b0) * s1;
          const float c1 = b1 + (b3 - b1) * s1;
          const float res = c0 + (c1 - c0) * s0;
          const int row = mb * 256 + wr * 64 + mt * 16 + (lane >> 4) * 4 + r;
          out[(size_t)row * O_DIM + o] = res;
        }
      }
    }
  }
}

// ---------------------------------------------------------------------------
extern "C" void kernel_launch(void* const* d_in, const int* in_sizes, int n_in,
                              void* d_out, int out_size, void* d_ws, size_t ws_size,
                              hipStream_t stream) {
  const float* x      = (const float*)d_in[0];  // (B, I)
  const float* logits = (const float*)d_in[1];  // (O, N, I)
  const float* lut    = (const float*)d_in[2];  // (O, 16)
  float* out          = (float*)d_out;          // (B, O)

  _Float16* wt = (_Float16*)d_ws;                                  // 8 MB tiled
  _Float16* xt = (_Float16*)d_ws + (size_t)ON_DIM * I_DIM;         // 8 MB tiled

  ltn_prep<<<2048, 256, 0, stream>>>(logits, x, wt, xt);
  ltn_gemm_lut<<<256, 512, 0, stream>>>(xt, wt, lut, out);
}

// Round 10
// 132.269 us; speedup vs baseline: 1.3682x; 1.0206x over previous
//
#include <hip/hip_runtime.h>

#define B_DIM 4096
#define I_DIM 1024
#define O_DIM 1024
#define ON_DIM 4096      // O * N fan-in columns
#define TILE_HALFS 4096  // one 128(m) x 32(k) fp16 tile image = 8 KB
                         // image order: [kb8(4)][m(128)][j(8)] halfs

typedef _Float16 half8  __attribute__((ext_vector_type(8)));
typedef _Float16 half4_t __attribute__((ext_vector_type(4)));
typedef float    floatx4  __attribute__((ext_vector_type(4)));
typedef float    floatx16 __attribute__((ext_vector_type(16)));

// ---------------------------------------------------------------------------
// Kernel P: fused prep (R7, kept) — softmax+tile in one pass, 2 launches.
// ---------------------------------------------------------------------------
__global__ __launch_bounds__(256)
void ltn_prep(const float* __restrict__ logits, const float* __restrict__ x,
              _Float16* __restrict__ wt, _Float16* __restrict__ xt) {
  const int t = threadIdx.x;
  if (blockIdx.x < 1024) {
    __shared__ _Float16 lbuf[4][1040];
    const int lane = t & 63, wv = t >> 6;
    const int row  = blockIdx.x * 4 + wv;          // ON row, 4-aligned base
    const int nb   = row >> 7;
    const int nnB  = (blockIdx.x * 4) & 127;       // base m within 128-tile
    const float4* s4 = (const float4*)(logits + (size_t)row * I_DIM);
    float4 v[4];
#pragma unroll
    for (int j = 0; j < 4; j++) v[j] = s4[lane * 4 + j];  // 64B/lane contig
    float m = -1e30f;
#pragma unroll
    for (int j = 0; j < 4; j++)
      m = fmaxf(m, fmaxf(fmaxf(v[j].x, v[j].y), fmaxf(v[j].z, v[j].w)));
#pragma unroll
    for (int off = 1; off < 64; off <<= 1) m = fmaxf(m, __shfl_xor(m, off));
    float s = 0.0f;
#pragma unroll
    for (int j = 0; j < 4; j++) {
      v[j].x = __expf(v[j].x - m); v[j].y = __expf(v[j].y - m);
      v[j].z = __expf(v[j].z - m); v[j].w = __expf(v[j].w - m);
      s += v[j].x + v[j].y + v[j].z + v[j].w;
    }
#pragma unroll
    for (int off = 1; off < 64; off <<= 1) s += __shfl_xor(s, off);
    const float inv = 1.0f / s;
#pragma unroll
    for (int j = 0; j < 4; j++) {
      half4_t h;
      h[0] = (_Float16)(v[j].x * inv); h[1] = (_Float16)(v[j].y * inv);
      h[2] = (_Float16)(v[j].z * inv); h[3] = (_Float16)(v[j].w * inv);
      *(half4_t*)&lbuf[wv][lane * 16 + j * 4] = h;   // k = lane*16+j*4..+3
    }
    __syncthreads();
#pragma unroll
    for (int p = 0; p < 2; p++) {
      const int u   = t + p * 256;
      const int nn4 = u & 3;
      const int kb8 = (u >> 2) & 3;
      const int kb  = u >> 4;
      const half8 h = *(const half8*)&lbuf[nn4][kb * 32 + kb8 * 8];
      _Float16* dst = wt + ((size_t)nb * 32 + kb) * TILE_HALFS
                    + kb8 * 1024 + (nnB + nn4) * 8;
      *(half8*)dst = h;
    }
  } else {
    const int bid = blockIdx.x - 1024;
    const int nn = t >> 1;        // row within 128-tile
    const int hf = t & 1;         // which 16-k half of the 32-k tile
    const int mb = bid >> 5, kt = bid & 31;
    const int row = mb * 128 + nn;
    const float4* src = (const float4*)(x + (size_t)row * I_DIM + kt * 32 + hf * 16);
    const float4 a = src[0], b = src[1], c = src[2], d = src[3];
    half8 h0, h1;
    h0[0] = (_Float16)a.x; h0[1] = (_Float16)a.y; h0[2] = (_Float16)a.z; h0[3] = (_Float16)a.w;
    h0[4] = (_Float16)b.x; h0[5] = (_Float16)b.y; h0[6] = (_Float16)b.z; h0[7] = (_Float16)b.w;
    h1[0] = (_Float16)c.x; h1[1] = (_Float16)c.y; h1[2] = (_Float16)c.z; h1[3] = (_Float16)c.w;
    h1[4] = (_Float16)d.x; h1[5] = (_Float16)d.y; h1[6] = (_Float16)d.z; h1[7] = (_Float16)d.w;
    _Float16* base = xt + ((size_t)mb * 32 + kt) * TILE_HALFS + (hf * 2) * 1024 + nn * 8;
    *(half8*)base = h0;
    *(half8*)(base + 1024) = h1;
  }
}

// ---------------------------------------------------------------------------
// GEMM + sigmoid + 16-corner LUT.  R10: R1's EXACT winning structure with
// ONE change — MFMA shape 16x16x32 -> 32x32x16. Same FLOPs, HALF the MFMA
// instructions (16 vs 32 per wave per k-tile), +15% per-instr rate (m119:
// 2382 vs 2075 TF), identical ds_read pattern (12 x b128/wave/k-tile).
// R0-R9 post-mortem: six schedule families all 48-50us WARM (R8 marginal-
// cost experiment) -> per-k-step cost is schedule-invariant; last untested
// lever is per-MFMA-instruction cost. A/B readout: warm total moves =>
// issue-bound (keep pushing); unchanged => latency wall (declare).
// Fragment mapping on our [kb8][m][j] image: A lane l -> row l&31,
// kb8 = kk*2 + (l>>5); B lane l -> col l&31, same kb8. C/D (m74/m101
// MEASURED): col = lane&31, row = (reg&3) + 8*(reg>>2) + 4*(lane>>5).
// ---------------------------------------------------------------------------
__global__ __launch_bounds__(512, 2)
void ltn_gemm_lut(const _Float16* __restrict__ xt,   // tiles [32*32][TILE_HALFS]
                  const _Float16* __restrict__ wt,
                  const float* __restrict__ lut,     // [O][16]
                  float* __restrict__ out) {         // [B][O]
  __shared__ _Float16 sm[3 * 16384];   // 3 x (A 16KB | B 16KB)

  const int tid  = threadIdx.x;
  const int lane = tid & 63;
  const int wv   = tid >> 6;     // 0..7
  const int wr   = wv >> 1;      // row-wave 0..3  (64 rows each)
  const int wc   = wv & 1;       // col-wave 0..1  (128 cols each)

  const int id  = blockIdx.x;    // 0..255
  const int xcd = id & 7;
  const int li  = id >> 3;       // 0..31
  const int mb  = (xcd & 3) * 4 + (li & 3);
  const int nb  = (xcd >> 2) * 8 + (li >> 2);

  const int l31 = lane & 31;
  const int lh  = lane >> 5;     // k-octet selector within kk-pair

  const size_t baseA = (size_t)(mb * 2) * 32 * TILE_HALFS;
  const size_t baseB = (size_t)(nb * 2) * 32 * TILE_HALFS;

  floatx16 acc[2][4];
#pragma unroll
  for (int i = 0; i < 2; i++)
#pragma unroll
    for (int j = 0; j < 4; j++) acc[i][j] = (floatx16)0.0f;

  auto stage = [&](int bufOff /*halfs*/, int kt) {
#pragma unroll
    for (int s = 0; s < 4; s++) {
      const int c   = wv * 4 + s;        // 0..31, wave-uniform split
      const int cc  = c & 15;            // chunk within matrix
      const int tl  = cc >> 3;           // which 128-row tile (0/1)
      const int sub = cc & 7;            // 1KB sub-chunk
      const _Float16* g;
      int dst;
      if (c < 16) {
        g = xt + baseA + (size_t)(tl * 32 + kt) * TILE_HALFS + sub * 512 + lane * 8;
        dst = bufOff + cc * 512;
      } else {
        g = wt + baseB + (size_t)(tl * 32 + kt) * TILE_HALFS + sub * 512 + lane * 8;
        dst = bufOff + 8192 + cc * 512;
      }
      __builtin_amdgcn_global_load_lds(
          (const __attribute__((address_space(1))) void*)g,
          (__attribute__((address_space(3))) void*)(sm + dst), 16, 0, 0);
    }
  };

  auto compute = [&](int bufOff) {
    half8 af[2][2], bf[2][4];
    // A: tl = wr>>1; m = (wr&1)*64 + mt*32 + l31; kb8 = kk*2 + lh
#pragma unroll
    for (int kk = 0; kk < 2; kk++)
#pragma unroll
      for (int mt = 0; mt < 2; mt++)
        af[kk][mt] = *(const half8*)&sm[bufOff + (wr >> 1) * 4096
                                        + (kk * 2 + lh) * 1024
                                        + ((wr & 1) * 64 + mt * 32 + l31) * 8];
    // B: tile wc; col = nt*32 + l31; same kb8
#pragma unroll
    for (int kk = 0; kk < 2; kk++)
#pragma unroll
      for (int nt = 0; nt < 4; nt++)
        bf[kk][nt] = *(const half8*)&sm[bufOff + 8192 + wc * 4096
                                        + (kk * 2 + lh) * 1024
                                        + (nt * 32 + l31) * 8];
    __builtin_amdgcn_s_setprio(1);
#pragma unroll
    for (int kk = 0; kk < 2; kk++)
#pragma unroll
      for (int mt = 0; mt < 2; mt++)
#pragma unroll
        for (int nt = 0; nt < 4; nt++)
          acc[mt][nt] = __builtin_amdgcn_mfma_f32_32x32x16_f16(
              af[kk][mt], bf[kk][nt], acc[mt][nt], 0, 0, 0);
    __builtin_amdgcn_s_setprio(0);
  };

  stage(0, 0);
  stage(16384, 1);
  int o0 = 0, o1 = 16384, o2 = 32768;   // read buf, in-flight buf, free buf

  for (int kt = 0; kt < 32; kt++) {
    if (kt < 31) asm volatile("s_waitcnt vmcnt(4)" ::: "memory");
    else         asm volatile("s_waitcnt vmcnt(0)" ::: "memory");
    __builtin_amdgcn_s_barrier();
    __builtin_amdgcn_sched_barrier(0);
    if (kt + 2 < 32) stage(o2, kt + 2);  // o2 held kt-1: reads done pre-barrier
    compute(o0);
    const int t0 = o0; o0 = o1; o1 = o2; o2 = t0;
  }

  // ---- fused epilogue: sigmoid -> gather 4 fan-in values -> LUT contraction
  // 32x32 C/D layout (m74/m101): col = lane&31, row = (r&3)+8*(r>>2)+4*lh.
  // 4 consecutive n (cols) of one o live in 4 consecutive lanes.
#pragma unroll
  for (int nt = 0; nt < 4; nt++) {
    const int o = (nb * 256 + wc * 128 + nt * 32 + l31) >> 2;
    const float4* lt4 = (const float4*)(lut + (size_t)o * 16);
    const float4 L0 = lt4[0], L1 = lt4[1], L2 = lt4[2], L3 = lt4[3];
#pragma unroll
    for (int mt = 0; mt < 2; mt++) {
#pragma unroll
      for (int r = 0; r < 16; r++) {
        const float v  = acc[mt][nt][r];
        const float sv = 1.0f / (1.0f + __expf(-v));
        const float s1 = __shfl_down(sv, 1);
        const float s2 = __shfl_down(sv, 2);
        const float s3 = __shfl_down(sv, 3);
        if ((lane & 3) == 0) {
          const float s0 = sv;
          const float a0 = L0.x + (L2.x - L0.x) * s3;
          const float a1 = L0.y + (L2.y - L0.y) * s3;
          const float a2 = L0.z + (L2.z - L0.z) * s3;
          const float a3 = L0.w + (L2.w - L0.w) * s3;
          const float a4 = L1.x + (L3.x - L1.x) * s3;
          const float a5 = L1.y + (L3.y - L1.y) * s3;
          const float a6 = L1.z + (L3.z - L1.z) * s3;
          const float a7 = L1.w + (L3.w - L1.w) * s3;
          const float b0 = a0 + (a4 - a0) * s2;
          const float b1 = a1 + (a5 - a1) * s2;
          const float b2 = a2 + (a6 - a2) * s2;
          const float b3 = a3 + (a7 - a3) * s2;
          const float c0 = b0 + (b2 - b0) * s1;
          const float c1 = b1 + (b3 - b1) * s1;
          const float res = c0 + (c1 - c0) * s0;
          const int row = mb * 256 + wr * 64 + mt * 32
                        + (r & 3) + 8 * (r >> 2) + 4 * lh;
          out[(size_t)row * O_DIM + o] = res;
        }
      }
    }
  }
}

// ---------------------------------------------------------------------------
extern "C" void kernel_launch(void* const* d_in, const int* in_sizes, int n_in,
                              void* d_out, int out_size, void* d_ws, size_t ws_size,
                              hipStream_t stream) {
  const float* x      = (const float*)d_in[0];  // (B, I)
  const float* logits = (const float*)d_in[1];  // (O, N, I)
  const float* lut    = (const float*)d_in[2];  // (O, 16)
  float* out          = (float*)d_out;          // (B, O)

  _Float16* wt = (_Float16*)d_ws;                                  // 8 MB tiled
  _Float16* xt = (_Float16*)d_ws + (size_t)ON_DIM * I_DIM;         // 8 MB tiled

  ltn_prep<<<2048, 256, 0, stream>>>(logits, x, wt, xt);
  ltn_gemm_lut<<<256, 512, 0, stream>>>(xt, wt, lut, out);
}